// Round 1
// 169.140 us; speedup vs baseline: 1.0274x; 1.0274x over previous
//
#include <hip/hip_runtime.h>
#include <math.h>

#define BDIM 64
#define HDIM 512
#define WDIM 512
#define KW   31
#define PAD  15
#define INV_KK (1.0f / 961.0f)
#define TH   32                       // output rows per block (grid 64x16 = 1024 blocks)
#define NPIX ((size_t)BDIM * HDIM * WDIM)

// acc[0]: bce sum; acc[1..64]: inter[b]; acc[65..128]: union[b]
#define NACC 129

__global__ void zero_acc_kernel(double* acc) {
    int i = threadIdx.x;
    if (i < NACC) acc[i] = 0.0;
}

// ---- DPP helpers: VALU cross-lane (no LDS pipe) -------------------------
template<int CTRL, int RMASK>
__device__ __forceinline__ float dpp_add(float p) {
    int t = __builtin_amdgcn_update_dpp(0, __builtin_bit_cast(int, p),
                                        CTRL, RMASK, 0xf, true);
    return p + __builtin_bit_cast(float, t);
}

// inclusive prefix sum over 64 lanes
__device__ __forceinline__ float wave_iscan(float p) {
    p = dpp_add<0x111, 0xf>(p);   // row_shr:1
    p = dpp_add<0x112, 0xf>(p);   // row_shr:2
    p = dpp_add<0x114, 0xf>(p);   // row_shr:4
    p = dpp_add<0x118, 0xf>(p);   // row_shr:8
    p = dpp_add<0x142, 0xa>(p);   // row_bcast:15 -> rows 1,3
    p = dpp_add<0x143, 0xc>(p);   // row_bcast:31 -> rows 2,3
    return p;
}

// inclusive prefix valid through lane 31 (we only use lanes 0..29)
__device__ __forceinline__ float wave_iscan30(float p) {
    p = dpp_add<0x111, 0xf>(p);
    p = dpp_add<0x112, 0xf>(p);
    p = dpp_add<0x114, 0xf>(p);
    p = dpp_add<0x118, 0xf>(p);
    p = dpp_add<0x142, 0xa>(p);
    return p;
}

// lane i <- lane i-1 (lane 0 -> 0): inclusive->exclusive shift
__device__ __forceinline__ float wave_shr1(float p) {
    int t = __builtin_amdgcn_update_dpp(0, __builtin_bit_cast(int, p),
                                        0x138 /*WAVE_SHR1*/, 0xf, 0xf, true);
    return __builtin_bit_cast(float, t);
}

// Vertical-first separable box filter, ring-free.
// One block per (image, 32-row tile). 512 threads, 8 waves; each wave owns a
// 64-column strip. Per thread: running vertical 31-row sums for its two halo
// columns (vsA at acol, vsB at bcol), updated by +row(r) - row(r-31), the
// latter RE-LOADED from global (L1/L2 hit: same block touched it 31 rows ago).
// Horizontal 31-box via DPP prefix scan runs only on the 32 EMIT rows (not all
// 62 input rows). No LDS ring -> LDS = 96 B -> 3-4 blocks/CU (24-32 waves/CU)
// vs the previous kernel's LDS-capped 16.
__global__ __launch_bounds__(512, 6)
void fused_kernel(const float* __restrict__ pred,
                  const float* __restrict__ mask,
                  double* __restrict__ acc) {
    __shared__ float red[3][8];

    const int b    = blockIdx.x;
    const int y0   = blockIdx.y * TH;
    const int x    = threadIdx.x;     // output column
    const int lane = x & 63;
    const int wv   = x >> 6;
    const int s    = wv * 64;         // strip start column

    const float* mbase = mask + (size_t)b * HDIM * WDIM;
    const float* pbase = pred + (size_t)b * HDIM * WDIM;

    const int acol = s - 15 + lane;             // halo column, pos 0..63
    const int bcol = s + 49 + lane;             // halo column, pos 64..93
    const bool a_ok = (acol >= 0) && (acol < WDIM);
    const bool b_ok = (lane < 30) && (bcol < WDIM);

    const int tstart = y0 - PAD;                // first row entering the vsum
    const int tend   = y0 + TH - 1 + PAD;       // last row (62 rows total)
    const int smax   = (tstart > 0) ? tstart : 0;  // earliest legally-subtracted row

    float vsA = 0.f, vsB = 0.f;                 // vertical 31-row column sums
    float bce_acc = 0.f, inter_acc = 0.f, uni_acc = 0.f;

    auto load_halo = [&](int row, float& A, float& B) {
        A = 0.f; B = 0.f;
        if (row >= 0 && row < HDIM) {
            const float* rp = mbase + (size_t)row * WDIM;
            if (a_ok) A = rp[acol];
            if (b_ok) B = rp[bcol];
        }
    };
    // subtracted row r-31: only valid once it actually entered the sum
    // (row >= tstart) and exists (row >= 0). row < HDIM guaranteed.
    auto load_sub = [&](int row, float& A, float& B) {
        A = 0.f; B = 0.f;
        if (row >= smax) {
            const float* rp = mbase + (size_t)row * WDIM;
            if (a_ok) A = rp[acol];
            if (b_ok) B = rp[bcol];
        }
    };
    // emit row yo = row - PAD; every row of the emit loop emits, gate is only
    // for prefetch past the tile end.
    auto load_emit = [&](int row, float& M, float& P) {
        M = 0.f; P = 0.f;
        if (row <= tend) {
            const size_t off = (size_t)(row - PAD) * WDIM + x;
            M = mbase[off];
            P = pbase[off];
        }
    };

    auto process = [&](float A, float B, float S, float T, float M, float P) {
        vsA += A - S;                       // slide vertical window
        vsB += B - T;
        float pa = wave_iscan(vsA);         // prefix over positions 0..63
        float pb = wave_iscan30(vsB);       // prefix over positions 64..93
        const float atot = __builtin_bit_cast(float,
            __builtin_amdgcn_readlane(__builtin_bit_cast(int, pa), 63));
        const float v1 = __shfl(pa, (lane + 30) & 63);
        const float v2 = __shfl(pb, (lane + 30) & 63);   // = pb[lane-34] for lane>=34
        const float Phi = (lane <= 33) ? v1 : (atot + v2);
        const float Plo = wave_shr1(pa);
        const float hs  = Phi - Plo;        // full 31x31 box sum

        const float box  = hs * INV_KK;
        const float weit = 1.f + 5.f * fabsf(box - M);
        const float e1   = __expf(-fabsf(P));
        const float bce  = fmaxf(P, 0.f) - P * M + __logf(1.f + e1);
        const float rr   = __builtin_amdgcn_rcpf(1.f + e1);
        const float sp   = (P >= 0.f) ? rr : e1 * rr;    // sigmoid from e1, saves an exp
        bce_acc   += bce;
        inter_acc += sp * M * weit;
        uni_acc   += (sp + M) * weit;
    };

    // ---- warmup: rows tstart .. y0+14 (30 rows, 15 iters), adds only ----
    float cA[2], cB[2];
    load_halo(tstart,     cA[0], cB[0]);
    load_halo(tstart + 1, cA[1], cB[1]);
    for (int t = tstart; t < y0 + PAD; t += 2) {
        float nA[2], nB[2];
        load_halo(t + 2, nA[0], nB[0]);
        load_halo(t + 3, nA[1], nB[1]);
        vsA += cA[0] + cA[1];
        vsB += cB[0] + cB[1];
        cA[0] = nA[0]; cA[1] = nA[1]; cB[0] = nB[0]; cB[1] = nB[1];
    }
    // cA/cB now hold rows y0+15, y0+16 (prefetched by the last warmup iter)

    // ---- emit: rows y0+15 .. y0+46 (32 rows, 16 iters), scan + emit ----
    float cS[2], cT[2], cM[2], cP[2];
    load_sub(y0 - 16, cS[0], cT[0]);        // (y0+15)-31: gated to 0 (not yet in sum)
    load_sub(y0 - 15, cS[1], cT[1]);        // (y0+16)-31: first real subtraction
    load_emit(y0 + PAD,     cM[0], cP[0]);
    load_emit(y0 + PAD + 1, cM[1], cP[1]);

    for (int t = y0 + PAD; t <= tend; t += 2) {
        float nA[2], nB[2], nS[2], nT[2], nM[2], nP[2];
        load_halo(t + 2, nA[0], nB[0]);
        load_halo(t + 3, nA[1], nB[1]);
        load_sub (t - 29, nS[0], nT[0]);    // (t+2)-31
        load_sub (t - 28, nS[1], nT[1]);    // (t+3)-31
        load_emit(t + 2, nM[0], nP[0]);
        load_emit(t + 3, nM[1], nP[1]);

        process(cA[0], cB[0], cS[0], cT[0], cM[0], cP[0]);
        process(cA[1], cB[1], cS[1], cT[1], cM[1], cP[1]);

        cA[0] = nA[0]; cA[1] = nA[1]; cB[0] = nB[0]; cB[1] = nB[1];
        cS[0] = nS[0]; cS[1] = nS[1]; cT[0] = nT[0]; cT[1] = nT[1];
        cM[0] = nM[0]; cM[1] = nM[1]; cP[0] = nP[0]; cP[1] = nP[1];
    }

    // ---- block reduction (8 waves) ----
#pragma unroll
    for (int off = 32; off > 0; off >>= 1) {
        bce_acc   += __shfl_down(bce_acc, off);
        inter_acc += __shfl_down(inter_acc, off);
        uni_acc   += __shfl_down(uni_acc, off);
    }
    if (lane == 0) {
        red[0][wv] = bce_acc;
        red[1][wv] = inter_acc;
        red[2][wv] = uni_acc;
    }
    __syncthreads();
    if (threadIdx.x == 0) {
        float bs = 0.f, is = 0.f, us = 0.f;
#pragma unroll
        for (int w = 0; w < 8; ++w) { bs += red[0][w]; is += red[1][w]; us += red[2][w]; }
        atomicAdd(&acc[0],      (double)bs);
        atomicAdd(&acc[1 + b],  (double)is);
        atomicAdd(&acc[65 + b], (double)us);
    }
}

__global__ void finalize_kernel(const double* __restrict__ acc, float* __restrict__ out) {
    const int b = threadIdx.x;   // one wave
    double inter = acc[1 + b];
    double uni   = acc[65 + b];
    double wiou  = 1.0 - (inter + 1.0) / (uni - inter + 1.0);
#pragma unroll
    for (int off = 32; off > 0; off >>= 1) wiou += __shfl_down(wiou, off);
    if (b == 0) {
        double wbce = acc[0] / (double)NPIX;
        out[0] = (float)(wbce + wiou / (double)BDIM);
    }
}

extern "C" void kernel_launch(void* const* d_in, const int* in_sizes, int n_in,
                              void* d_out, int out_size, void* d_ws, size_t ws_size,
                              hipStream_t stream) {
    const float* pred = (const float*)d_in[0];
    const float* mask = (const float*)d_in[1];
    float* out = (float*)d_out;
    double* acc = (double*)d_ws;

    zero_acc_kernel<<<1, 256, 0, stream>>>(acc);

    dim3 grid(BDIM, HDIM / TH);
    fused_kernel<<<grid, WDIM, 0, stream>>>(pred, mask, acc);

    finalize_kernel<<<1, 64, 0, stream>>>(acc, out);
}